// Round 10
// baseline (391.962 us; speedup 1.0000x reference)
//
#include <hip/hip_runtime.h>
#include <cstddef>

#define TPB 256

typedef unsigned short ushort_t;
typedef __attribute__((ext_vector_type(8))) short s8v;
typedef __attribute__((ext_vector_type(4))) float f4v;
typedef __attribute__((ext_vector_type(4))) unsigned u4v;

#define MFMA16(a, b, c) __builtin_amdgcn_mfma_f32_16x16x32_bf16((a), (b), (c), 0, 0, 0)

static const int NB   = 32;    // batch
static const int NPIX = 1024;  // 32x32
static const int CIN  = 264;
static const int C1   = 128;
static const int C2   = 256;
static const int VF_  = 258;
static const int DS_  = 300;
static const int LL   = 20;

__device__ __forceinline__ ushort_t f2b(float x) {
  unsigned u = __builtin_bit_cast(unsigned, x);
  u = (u + 0x7fffu + ((u >> 16) & 1u)) >> 16;
  return (ushort_t)u;
}

// ---------------- fused prep kernel ----------------
__global__ __launch_bounds__(TPB) void k_prep(
    const float* __restrict__ c1w, const float* __restrict__ c2w,
    const float* __restrict__ rw, const float* __restrict__ kw,
    const float* __restrict__ qw, const float* __restrict__ vw,
    const float* __restrict__ txt, const float* __restrict__ iw,
    const float* __restrict__ ib,
    const float* __restrict__ video, const float* __restrict__ spatial,
    ushort_t* __restrict__ w1r, ushort_t* __restrict__ w2r,
    ushort_t* __restrict__ wcat,
    float* __restrict__ mod, ushort_t* __restrict__ x0h) {
  int bid = blockIdx.x;
  const int tid = threadIdx.x;

  if (bid < 1296) {  // wreorder2 conv1
    int i = bid * TPB + tid;
    if (i < 9 * 9 * 128 * 32) {
      int j = i & 31;
      int oc = (i >> 5) % 128;
      int ts = (i >> 5) / 128;
      int s = ts % 9, t = ts / 9;
      int ic = s * 32 + j;
      float v = (ic < 264) ? c1w[((size_t)oc * 264 + ic) * 9 + t] : 0.f;
      w1r[i] = f2b(v);
    }
    return;
  }
  bid -= 1296;
  if (bid < 1152) {  // wreorder2 conv2
    int i = bid * TPB + tid;
    if (i < 9 * 4 * 256 * 32) {
      int j = i & 31;
      int oc = (i >> 5) % 256;
      int ts = (i >> 5) / 256;
      int s = ts % 4, t = ts / 4;
      int ic = s * 32 + j;
      float v = (ic < 128) ? c2w[((size_t)oc * 128 + ic) * 9 + t] : 0.f;
      w2r[i] = f2b(v);
    }
    return;
  }
  bid -= 1152;
  if (bid < 4 * 432) {  // wprep x4 -> wcat segments (0:rw 1:kw 2:qw 3:vw)
    int which = bid / 432;
    int i = (bid - which * 432) * TPB + tid;
    if (i < 384 * 288) {
      int n = i / 288, k = i - n * 288;
      const float* src = (which == 0) ? rw : (which == 1) ? kw : (which == 2) ? qw : vw;
      int N = (which == 0) ? 300 : 258;
      float v = (n < N && k < 258) ? src[(size_t)n * 258 + k] : 0.f;
      wcat[(size_t)which * 110592 + i] = f2b(v);
    }
    return;
  }
  bid -= 4 * 432;
  if (bid < 32) {  // tmaxmod, b = bid
    int b = bid;
    __shared__ float tm[DS_];
    for (int d = tid; d < DS_; d += TPB) {
      const float* p = txt + ((size_t)b * DS_ + d) * LL;
      float m = p[0];
      for (int l = 1; l < LL; ++l) m = fmaxf(m, p[l]);
      tm[d] = m;
    }
    __syncthreads();
    for (int oc = tid; oc < VF_; oc += TPB) {
      const float* wr = iw + (size_t)oc * DS_;
      float s = ib[oc];
      for (int d = 0; d < DS_; ++d) s += tm[d] * wr[d];
      mod[(size_t)b * VF_ + oc] = s;
    }
    return;
  }
  bid -= 32;
  {  // cat_nhwc
    const int pb = bid & 15;
    const int b = bid >> 4;
    __shared__ ushort_t lds[264][72];
    for (int u = tid; u < 264 * 64; u += TPB) {
      int c = u >> 6, px = u & 63;
      int p = (pb << 6) + px;
      float v = (c < 256) ? video[(((size_t)b * 256 + c) << 10) + p]
                          : spatial[(((size_t)b * 8 + (c - 256)) << 10) + p];
      lds[c][px] = f2b(v);
    }
    __syncthreads();
    for (int u = tid; u < 64 * 36; u += TPB) {
      int px = u / 36, ch = u - px * 36;
      s8v v;
#pragma unroll
      for (int j = 0; j < 8; ++j) {
        int ic = ch * 8 + j;
        v[j] = (ic < 264) ? (short)lds[ic][px] : (short)0;
      }
      *(s8v*)(x0h + ((size_t)((b << 10) + (pb << 6) + px)) * 288 + ch * 8) = v;
    }
  }
}

// ---------------- conv 3x3 via bf16 MFMA implicit GEMM (+GN stats) ----------------
template <int ICG>
__global__ __launch_bounds__(TPB) void k_conv_mfma(const ushort_t* __restrict__ in_h,
                                                   const ushort_t* __restrict__ wr,
                                                   const float* __restrict__ bias,
                                                   float* __restrict__ out,
                                                   float* __restrict__ stats, int Cout) {
  const int ICPAD = ICG * 8;
  const int NS = ICG / 4;
  const int ICGS = 4 * 34 * 8 + 24;
  const int b   = blockIdx.z;
  const int ocb = blockIdx.y << 7;
  const int pxb = blockIdx.x;
  const int tid = threadIdx.x;
  const int w = tid >> 6, lane = tid & 63;
  const int lhi = lane >> 4, llo = lane & 15;

  __shared__ ushort_t in_t[ICG * ICGS];

  for (int u = tid; u < ICG * 8; u += TPB) {
    int icg = u >> 3, rem = u & 7, row = rem >> 1, col = (rem & 1) ? 33 : 0;
    *(s8v*)&in_t[icg * ICGS + (row * 34 + col) * 8] = (s8v){0, 0, 0, 0, 0, 0, 0, 0};
  }
  for (int r = 0; r < 4; ++r) {
    int gy = (pxb << 1) - 1 + r;
    if ((unsigned)gy < 32u) {
      const ushort_t* src = in_h + ((size_t)((b << 10) + (gy << 5))) * ICPAD;
      for (int u = tid; u < 32 * ICG; u += TPB) {
        int px = u / ICG, icg = u - px * ICG;
        *(s8v*)&in_t[icg * ICGS + (r * 34 + px + 1) * 8] = *(const s8v*)(src + u * 8);
      }
    } else {
      for (int u = tid; u < 32 * ICG; u += TPB) {
        int px = u / ICG, icg = u - px * ICG;
        *(s8v*)&in_t[icg * ICGS + (r * 34 + px + 1) * 8] = (s8v){0, 0, 0, 0, 0, 0, 0, 0};
      }
    }
  }
  __syncthreads();

  f4v acc[2][4];
#pragma unroll
  for (int i = 0; i < 2; ++i)
#pragma unroll
    for (int m = 0; m < 4; ++m) acc[i][m] = (f4v){0.f, 0.f, 0.f, 0.f};

  for (int t = 0; t < 9; ++t) {
    const int ky = t / 3, kx = t - ky * 3;
#pragma unroll
    for (int s = 0; s < NS; ++s) {
      const ushort_t* wp = wr + (((size_t)(t * NS + s) * Cout + ocb + w * 32 + llo) << 5) + lhi * 8;
      s8v a0 = *(const s8v*)(wp);
      s8v a1 = *(const s8v*)(wp + (16 << 5));
      const int icg = (s << 2) + lhi;
#pragma unroll
      for (int m = 0; m < 4; ++m) {
        const int row = (m >> 1) + ky;
        const int col = ((m & 1) << 4) + llo + kx;
        s8v bm = *(const s8v*)&in_t[icg * ICGS + (row * 34 + col) * 8];
        acc[0][m] = MFMA16(a0, bm, acc[0][m]);
        acc[1][m] = MFMA16(a1, bm, acc[1][m]);
      }
    }
  }

#pragma unroll
  for (int i = 0; i < 2; ++i) {
#pragma unroll
    for (int r = 0; r < 4; ++r) {
      const int oc = ocb + w * 32 + i * 16 + lhi * 4 + r;
      const float bv = bias[oc];
      float sm = 0.f, sq = 0.f;
#pragma unroll
      for (int m = 0; m < 4; ++m) {
        const int px = (pxb << 6) + (m << 4) + llo;
        float v = acc[i][m][r] + bv;
        out[(((size_t)b * Cout + oc) << 10) + px] = v;
        sm += v;
        sq += v * v;
      }
#pragma unroll
      for (int off = 1; off < 16; off <<= 1) {
        sm += __shfl_xor(sm, off);
        sq += __shfl_xor(sq, off);
      }
      if (llo == 0) {
        size_t sidx = ((((size_t)b * Cout + oc) << 4) + pxb) << 1;
        stats[sidx] = sm;
        stats[sidx + 1] = sq;
      }
    }
  }
}

// ---------------- GN finalize ----------------
__global__ __launch_bounds__(64) void k_gnfin(const float* __restrict__ stats,
                                              const float* __restrict__ gamma,
                                              const float* __restrict__ beta,
                                              float* __restrict__ scale,
                                              float* __restrict__ shift,
                                              int C, int cpg) {
  const int g = blockIdx.x, b = blockIdx.y;
  const int n = cpg << 4;
  float s = 0.f, q = 0.f;
  for (int i = threadIdx.x; i < n; i += 64) {
    int c = g * cpg + (i >> 4), pxb = i & 15;
    size_t idx = ((((size_t)b * C + c) << 4) + pxb) << 1;
    s += stats[idx];
    q += stats[idx + 1];
  }
#pragma unroll
  for (int off = 32; off > 0; off >>= 1) {
    s += __shfl_xor(s, off);
    q += __shfl_xor(q, off);
  }
  const float M = (float)(cpg << 10);
  float mean = s / M;
  float rsig = rsqrtf(q / M - mean * mean + 1e-5f);
  if ((int)threadIdx.x < cpg) {
    int c = g * cpg + threadIdx.x;
    float sc = rsig * gamma[c];
    scale[(size_t)b * C + c] = sc;
    shift[(size_t)b * C + c] = beta[c] - mean * sc;
  }
}

// ---------------- c-major fp32 -> NHWC bf16 with fused GN+ReLU ----------------
__global__ __launch_bounds__(TPB) void k_to_nhwc128(const float* __restrict__ src,
                                                    const float* __restrict__ scale,
                                                    const float* __restrict__ shift,
                                                    ushort_t* __restrict__ dst) {
  const int pb = blockIdx.x;
  const int b  = blockIdx.y;
  const int tid = threadIdx.x;
  __shared__ ushort_t lds[128][72];
  for (int u = tid; u < 128 * 64; u += TPB) {
    int c = u >> 6, px = u & 63;
    int p = (pb << 6) + px;
    float v = src[(((size_t)b * 128 + c) << 10) + p];
    v = fmaxf(v * scale[(size_t)b * 128 + c] + shift[(size_t)b * 128 + c], 0.f);
    lds[c][px] = f2b(v);
  }
  __syncthreads();
  for (int u = tid; u < 64 * 16; u += TPB) {
    int px = u >> 4, ch = u & 15;
    s8v v;
#pragma unroll
    for (int j = 0; j < 8; ++j) v[j] = (short)lds[ch * 8 + j][px];
    *(s8v*)(dst + ((size_t)((b << 10) + (pb << 6) + px)) * 128 + ch * 8) = v;
  }
}

// y2 + fused GN+ReLU + coords -> vso_h bf16 [b][1024][288]
__global__ __launch_bounds__(TPB) void k_build_vsoh(const float* __restrict__ y2,
                                                    const float* __restrict__ scale,
                                                    const float* __restrict__ shift,
                                                    ushort_t* __restrict__ dst) {
  const int pb = blockIdx.x;
  const int b  = blockIdx.y;
  const int tid = threadIdx.x;
  __shared__ ushort_t lds[256][72];
  for (int u = tid; u < 256 * 64; u += TPB) {
    int c = u >> 6, px = u & 63;
    int p = (pb << 6) + px;
    float v = y2[(((size_t)b * 256 + c) << 10) + p];
    v = fmaxf(v * scale[(size_t)b * 256 + c] + shift[(size_t)b * 256 + c], 0.f);
    lds[c][px] = f2b(v);
  }
  __syncthreads();
  for (int u = tid; u < 64 * 36; u += TPB) {
    int px = u / 36, ch = u - px * 36;
    int p = (pb << 6) + px;
    s8v v;
#pragma unroll
    for (int j = 0; j < 8; ++j) {
      int cg = ch * 8 + j;
      float fv;
      if (cg < 256)      { v[j] = (short)lds[cg][px]; continue; }
      else if (cg == 256) fv = -1.f + (2.f / 31.f) * (float)(p & 31);
      else if (cg == 257) fv = -1.f + (2.f / 31.f) * (float)(p >> 5);
      else                fv = 0.f;
      v[j] = (short)f2b(fv);
    }
    *(s8v*)(dst + ((size_t)((b << 10) + p)) * 288 + ch * 8) = v;
  }
}

// ---------------- merged bf16 MFMA GEMM: all 4 projections in one dispatch ----------------
// blockIdx.x: 0-2 vsr (seg0), 3-5 k (seg1), 6-8 q (seg2), 9-11 v (seg3); n0 = (x%3)*128
__global__ __launch_bounds__(TPB) void k_gemm_all(const ushort_t* __restrict__ A,
                                                  const ushort_t* __restrict__ Wcat,
                                                  float* __restrict__ vsrT,
                                                  ushort_t* __restrict__ kb16,
                                                  ushort_t* __restrict__ qb16,
                                                  ushort_t* __restrict__ vtb16,
                                                  const float* __restrict__ rb,
                                                  const float* __restrict__ kb,
                                                  const float* __restrict__ qb,
                                                  const float* __restrict__ vb,
                                                  const float* __restrict__ mod) {
  const int b = blockIdx.z;
  const int seg = blockIdx.x / 3;
  const int n0 = (blockIdx.x - seg * 3) << 7;
  const int m0 = blockIdx.y << 7;
  const int tid = threadIdx.x;
  const int w = tid >> 6, lane = tid & 63;
  const int wr = w >> 1, wc = w & 1;
  const int lhi = lane >> 4, llo = lane & 15;

  const ushort_t* Bw = Wcat + (size_t)seg * 110592;
  const float* bias = (seg == 0) ? rb : (seg == 1) ? kb : (seg == 2) ? qb : vb;
  const bool swapAB = (seg == 0) || (seg == 3);

  __shared__ ushort_t A_l[128][40];
  __shared__ ushort_t B_l[128][40];

  f4v acc[4][4];
#pragma unroll
  for (int i = 0; i < 4; ++i)
#pragma unroll
    for (int j = 0; j < 4; ++j) acc[i][j] = (f4v){0.f, 0.f, 0.f, 0.f};

  const ushort_t* Ab = A + (((size_t)b << 10)) * 288;

  for (int k0 = 0; k0 < 288; k0 += 32) {
    for (int u = tid; u < 512; u += TPB) {
      int row = u >> 2, seg2 = u & 3;
      *(s8v*)&A_l[row][seg2 * 8] = *(const s8v*)(Ab + (size_t)(m0 + row) * 288 + k0 + seg2 * 8);
      *(s8v*)&B_l[row][seg2 * 8] = *(const s8v*)(Bw + (size_t)(n0 + row) * 288 + k0 + seg2 * 8);
    }
    __syncthreads();
    s8v am[4], bn[4];
#pragma unroll
    for (int i = 0; i < 4; ++i) am[i] = *(const s8v*)&A_l[wr * 64 + i * 16 + llo][lhi * 8];
#pragma unroll
    for (int j = 0; j < 4; ++j) bn[j] = *(const s8v*)&B_l[wc * 64 + j * 16 + llo][lhi * 8];
    if (swapAB) {
#pragma unroll
      for (int i = 0; i < 4; ++i)
#pragma unroll
        for (int j = 0; j < 4; ++j) acc[i][j] = MFMA16(bn[j], am[i], acc[i][j]);
    } else {
#pragma unroll
      for (int i = 0; i < 4; ++i)
#pragma unroll
        for (int j = 0; j < 4; ++j) acc[i][j] = MFMA16(am[i], bn[j], acc[i][j]);
    }
    __syncthreads();
  }

  if (seg == 0) {
    // fp32 transposed [300][1024]
    float* Cf = vsrT + (size_t)b * 300 * 1024;
#pragma unroll
    for (int j = 0; j < 4; ++j)
#pragma unroll
      for (int r = 0; r < 4; ++r) {
        int n = n0 + wc * 64 + j * 16 + lhi * 4 + r;
        if (n >= 300) continue;
        float bv = bias[n];
#pragma unroll
        for (int i = 0; i < 4; ++i) {
          int m = m0 + wr * 64 + i * 16 + llo;
          Cf[((size_t)n << 10) + m] = acc[i][j][r] + bv;
        }
      }
  } else if (seg == 1 || seg == 2) {
    ushort_t* Cb = ((seg == 1) ? kb16 : qb16) + (size_t)b * 1024 * 288;
#pragma unroll
    for (int j = 0; j < 4; ++j) {
      int n = n0 + wc * 64 + j * 16 + llo;
      if (n >= 288) continue;
      bool real = n < VF_;
      float bv = real ? bias[n] : 0.f;
      float sm = real ? mod[(size_t)b * VF_ + n] : 0.f;
#pragma unroll
      for (int i = 0; i < 4; ++i)
#pragma unroll
        for (int r = 0; r < 4; ++r) {
          int m = m0 + wr * 64 + i * 16 + lhi * 4 + r;
          Cb[(size_t)m * 288 + n] = f2b(real ? (acc[i][j][r] + bv) * sm : 0.f);
        }
    }
  } else {
    // chunk-blocked transposed store: Vt_blk[b][m>>5][n][m&31]
    ushort_t* Cb = vtb16 + (size_t)b * 32 * 272 * 32;
#pragma unroll
    for (int j = 0; j < 4; ++j)
#pragma unroll
      for (int r = 0; r < 4; ++r) {
        int n = n0 + wc * 64 + j * 16 + lhi * 4 + r;
        if (n >= 272) continue;
        bool real = n < VF_;
        float bv = real ? bias[n] : 0.f;
#pragma unroll
        for (int i = 0; i < 4; ++i) {
          int m = m0 + wr * 64 + i * 16 + llo;
          int mc = m >> 5, mlo = m & 31;
          Cb[(((size_t)mc * 272 + n) << 5) + mlo] = f2b(real ? acc[i][j][r] + bv : 0.f);
        }
      }
  }
}

// ---------------- txt cross-attention (vsr transposed [b][300][1024]) ----------------
__global__ __launch_bounds__(TPB) void k_txtattn(const float* __restrict__ vsrT,
                                                 const float* __restrict__ txt,
                                                 float* __restrict__ out) {
  const int b = blockIdx.y;
  const int p = blockIdx.x * TPB + threadIdx.x;
  __shared__ float tl[DS_ * LL];
  for (int i = threadIdx.x; i < DS_ * LL; i += TPB) tl[i] = txt[(size_t)b * DS_ * LL + i];
  __syncthreads();
  const float* vr = vsrT + ((size_t)b * DS_ << 10) + p;
  float lg[LL];
#pragma unroll
  for (int l = 0; l < LL; ++l) lg[l] = 0.f;
  for (int d = 0; d < DS_; d += 4) {
    float v0 = vr[(size_t)(d + 0) << 10];
    float v1 = vr[(size_t)(d + 1) << 10];
    float v2 = vr[(size_t)(d + 2) << 10];
    float v3 = vr[(size_t)(d + 3) << 10];
    const float* tr = tl + d * LL;
#pragma unroll
    for (int l = 0; l < LL; ++l)
      lg[l] += v0 * tr[l] + v1 * tr[l + 20] + v2 * tr[l + 40] + v3 * tr[l + 60];
  }
  const float sc = 0.057735026919f;
  float mx = lg[0] * sc;
#pragma unroll
  for (int l = 1; l < LL; ++l) mx = fmaxf(mx, lg[l] * sc);
  float sum = 0.f;
#pragma unroll
  for (int l = 0; l < LL; ++l) {
    lg[l] = __expf(lg[l] * sc - mx);
    sum += lg[l];
  }
  float inv = 1.f / sum;
#pragma unroll
  for (int l = 0; l < LL; ++l) lg[l] *= inv;
  float* ob = out + (((size_t)b * 558 + VF_) << 10) + p;
  for (int d = 0; d < DS_; ++d) {
    const float* tr = tl + d * LL;
    float s = 0.f;
#pragma unroll
    for (int l = 0; l < LL; ++l) s += lg[l] * tr[l];
    ob[(size_t)d << 10] = s;
  }
}

// ---------------- video self-attention: bf16 MFMA flash v3 ----------------
// K,Q: bf16 [b][1024][288]. Vt_blk: bf16 [b][32][272][32].
// Q in LDS as fragment-contiguous blocks (conflict-free b128); V direct from L2.
__global__ __launch_bounds__(256, 2) void k_flash_mfma(const ushort_t* __restrict__ Kb,
                                                       const ushort_t* __restrict__ Qb,
                                                       const ushort_t* __restrict__ Vtb,
                                                       float* __restrict__ out) {
  const int wg = blockIdx.x;           // 0..511
  const int xcd = wg & 7, s = wg >> 3;
  const int b = xcd * 4 + (s >> 4);
  const int n0 = (s & 15) << 6;
  const int tid = threadIdx.x;
  const int w = tid >> 6, lane = tid & 63;
  const int lhi = lane >> 4;
  const int llo = lane & 15;

  // q_blk[ks][row 0..31][32 elems], per-ks stride 1032 elems (8-elem rotation pad)
  __shared__ ushort_t q_l[9 * 1032];

  s8v kf[9];
  {
    const ushort_t* kp = Kb + ((size_t)(b * 1024 + n0 + w * 16 + llo)) * 288 + lhi * 8;
#pragma unroll
    for (int ks = 0; ks < 9; ++ks) kf[ks] = *(const s8v*)(kp + ks * 32);
  }

  const ushort_t* Qbase = Qb + (((size_t)b << 10)) * 288;
  const ushort_t* Vbase = Vtb + (size_t)b * 32 * 272 * 32;

  s8v qs[5];
  auto ISSUE = [&](int mc) {
#pragma unroll
    for (int i = 0; i < 5; ++i) {
      int u = tid + (i << 8);
      if (u < 1152) qs[i] = *(const s8v*)(Qbase + (size_t)((mc << 5) + u / 36) * 288 + (u % 36) * 8);
    }
  };
  auto WRITE = [&]() {
#pragma unroll
    for (int i = 0; i < 5; ++i) {
      int u = tid + (i << 8);
      if (u < 1152) {
        int r = u / 36, cq = u - r * 36;
        *(s8v*)&q_l[(cq >> 2) * 1032 + (r << 5) + ((cq & 3) << 3)] = qs[i];
      }
    }
  };

  f4v oacc[17];
#pragma unroll
  for (int i = 0; i < 17; ++i) oacc[i] = (f4v){0.f, 0.f, 0.f, 0.f};
  float mreg = -1e30f, lreg = 0.f;  // per-lane column n = n0 + w*16 + llo

  const float sc = 0.0622572819f;  // 1/sqrt(258)
  const int srcA = llo + ((lhi & 1) << 5);
  const int srcB = srcA + 16;
  const bool hi2 = lhi >= 2;
  const int qoff = (llo << 5) + (lhi << 3);  // lane offset within a q fragment block

  ISSUE(0);
  WRITE();
  __syncthreads();
  ISSUE(1);

  for (int mc = 0; mc < 32; ++mc) {
    const ushort_t* Vc = Vbase + (size_t)mc * 8704 + qoff;  // same (llo,lhi) tiling

    // V prefetch group A (consumed in PV dt 0..8)
    s8v va[9];
#pragma unroll
    for (int dt = 0; dt < 9; ++dt) va[dt] = *(const s8v*)(Vc + (dt << 9));

    // S^T[m][n] via swapped QK^T
    f4v sacc0 = {0.f, 0.f, 0.f, 0.f}, sacc1 = {0.f, 0.f, 0.f, 0.f};
    __builtin_amdgcn_s_setprio(1);
#pragma unroll
    for (int ks = 0; ks < 9; ++ks) {
      s8v q0 = *(const s8v*)&q_l[ks * 1032 + qoff];
      s8v q1 = *(const s8v*)&q_l[ks * 1032 + 512 + qoff];
      sacc0 = MFMA16(q0, kf[ks], sacc0);
      sacc1 = MFMA16(q1, kf[ks], sacc1);
    }
    __builtin_amdgcn_s_setprio(0);

    // V prefetch group B (consumed in PV dt 9..16)
    s8v vb[8];
#pragma unroll
    for (int dt = 0; dt < 8; ++dt) vb[dt] = *(const s8v*)(Vc + ((dt + 9) << 9));

    // lane-local online softmax
    float pmax = fmaxf(fmaxf(fmaxf(sacc0[0], sacc0[1]), fmaxf(sacc0[2], sacc0[3])),
                       fmaxf(fmaxf(sacc1[0], sacc1[1]), fmaxf(sacc1[2], sacc1[3])));
    pmax = fmaxf(pmax, __shfl_xor(pmax, 16));
    pmax = fmaxf(pmax, __shfl_xor(pmax, 32));
    float mn = fmaxf(mreg, pmax * sc);
    float alpha = __expf(mreg - mn);
    mreg = mn;

    float p0[4], p1[4];
    float rsum = 0.f;
#pragma unroll
    for (int r = 0; r < 4; ++r) {
      p0[r] = __expf(sacc0[r] * sc - mn);
      p1[r] = __expf(sacc1[r] * sc - mn);
      rsum += p0[r] + p1[r];
    }
    rsum += __shfl_xor(rsum, 16);
    rsum += __shfl_xor(rsum, 32);
    lreg = lreg * alpha + rsum;

    // pack P -> bf16 PV B-fragment
    unsigned u0, u1, u2, u3;
    asm("v_cvt_pk_bf16_f32 %0, %1, %2" : "=v"(u0) : "v"(p0[0]), "v"(p0[1]));
    asm("v_cvt_pk_bf16_f32 %0, %1, %2" : "=v"(u1) : "v"(p0[2]), "v"(p0[3]));
    asm("v_cvt_pk_bf16_f32 %0, %1, %2" : "=v"(u2) : "v"(p1[0]), "v"(p1[1]));
    asm("v_cvt_pk_bf16_f32 %0, %1, %2" : "=v"(u3) : "v"(p1[2]), "v"(p1[3]));
    unsigned s0a = __shfl(u0, srcA, 64), s2a = __shfl(u2, srcA, 64);
    unsigned s1a = __shfl(u1, srcA, 64), s3a = __shfl(u3, srcA, 64);
    unsigned s0b = __shfl(u0, srcB, 64), s2b = __shfl(u2, srcB, 64);
    unsigned s1b = __shfl(u1, srcB, 64), s3b = __shfl(u3, srcB, 64);
    u4v pu;
    pu[0] = hi2 ? s2a : s0a;
    pu[1] = hi2 ? s3a : s1a;
    pu[2] = hi2 ? s2b : s0b;
    pu[3] = hi2 ? s3b : s1b;
    s8v pf = __builtin_bit_cast(s8v, pu);

    // PV: O^T[d][n] += Vt_frag * P
    __builtin_amdgcn_s_setprio(1);
#pragma unroll
    for (int dt = 0; dt < 17; ++dt) {
      s8v vf = (dt < 9) ? va[dt] : vb[dt - 9];
      f4v o = oacc[dt];
      o[0] *= alpha; o[1] *= alpha; o[2] *= alpha; o[3] *= alpha;
      oacc[dt] = MFMA16(vf, pf, o);
    }
    __builtin_amdgcn_s_setprio(0);

    __syncthreads();  // all waves done reading q_l chunk mc
    if (mc < 31) {
      WRITE();        // chunk mc+1 -> LDS
      __syncthreads();
      if (mc < 30) ISSUE(mc + 2);
    }
  }

  // epilogue
  float linv = 1.f / lreg;
  const int n = n0 + w * 16 + llo;
#pragma unroll
  for (int dt = 0; dt < 17; ++dt) {
#pragma unroll
    for (int r = 0; r < 4; ++r) {
      int d = dt * 16 + lhi * 4 + r;
      if (d < VF_) out[((size_t)(b * 558 + d) << 10) + n] = oacc[dt][r] * linv;
    }
  }
}

// ---------------- launcher ----------------
extern "C" void kernel_launch(void* const* d_in, const int* in_sizes, int n_in,
                              void* d_out, int out_size, void* d_ws, size_t ws_size,
                              hipStream_t stream) {
  const float* spatial = (const float*)d_in[0];
  const float* video   = (const float*)d_in[1];
  const float* txt     = (const float*)d_in[2];
  const float* c1w = (const float*)d_in[3];
  const float* c1b = (const float*)d_in[4];
  const float* g1g = (const float*)d_in[5];
  const float* g1b = (const float*)d_in[6];
  const float* c2w = (const float*)d_in[7];
  const float* c2b = (const float*)d_in[8];
  const float* g2g = (const float*)d_in[9];
  const float* g2b = (const float*)d_in[10];
  const float* rw  = (const float*)d_in[11];
  const float* rb  = (const float*)d_in[12];
  const float* kw  = (const float*)d_in[13];
  const float* kb  = (const float*)d_in[14];
  const float* qw  = (const float*)d_in[15];
  const float* qb  = (const float*)d_in[16];
  const float* vw  = (const float*)d_in[17];
  const float* vb  = (const float*)d_in[18];
  const float* iw  = (const float*)d_in[19];
  const float* ib  = (const float*)d_in[20];
  float* out = (float*)d_out;
  float* ws = (float*)d_ws;

  // ws layout (float offsets), lifetime-aliased
  ushort_t* x0h    = (ushort_t*)(ws + 0);          // [0, 4.72M) -> conv1
  float*    vsr    = ws + 0;                       // [0, 9.83M)  (transposed [300][1024]) after x1h dead
  float*    y1     = ws + 5000000;                 // [5.0M, 9.2M)
  ushort_t* x1h    = (ushort_t*)(ws + 9300000);    // [9.3M, 11.4M)
  ushort_t* kb16   = (ushort_t*)(ws + 10000000);   // [10.0M, 14.72M)  after x1h dead
  float*    y2     = ws + 11500000;                // [11.5M, 19.9M)
  ushort_t* qb16   = (ushort_t*)(ws + 14800000);   // [14.8M, 19.52M)  after y2 dead
  ushort_t* vsoh   = (ushort_t*)(ws + 20000000);   // [20.0M, 24.72M)
  ushort_t* vtb16  = (ushort_t*)(ws + 24800000);   // [24.8M, 29.26M)
  ushort_t* wcat   = (ushort_t*)(ws + 29300000);   // 4*110592 us
  ushort_t* w1r    = (ushort_t*)(ws + 29540000);
  ushort_t* w2r    = (ushort_t*)(ws + 29710000);
  float*    mod    = ws + 29860000;                // 8,256
  float*    stats1 = ws + 29900000;                // 131,072
  float*    stats2 = ws + 30100000;                // 262,144
  float*    scale1 = ws + 30400000;                // 4,096
  float*    shift1 = ws + 30410000;                // 4,096
  float*    scale2 = ws + 30420000;                // 8,192
  float*    shift2 = ws + 30430000;                // 8,192

  // all prep (weights, mod, concat) in one dispatch
  k_prep<<<dim3(4720), TPB, 0, stream>>>(c1w, c2w, rw, kw, qw, vw, txt, iw, ib,
                                         video, spatial,
                                         w1r, w2r, wcat, mod, x0h);

  // conv1 (MFMA + GN stats); finalize; transpose+GN+relu -> x1h
  k_conv_mfma<36><<<dim3(16, 1, NB), TPB, 0, stream>>>(x0h, w1r, c1b, y1, stats1, C1);
  k_gnfin<<<dim3(32, NB), 64, 0, stream>>>(stats1, g1g, g1b, scale1, shift1, C1, 4);
  k_to_nhwc128<<<dim3(16, NB), TPB, 0, stream>>>(y1, scale1, shift1, x1h);

  // conv2 (MFMA + GN stats); finalize; vsoh (GN+relu+coords)
  k_conv_mfma<16><<<dim3(16, 2, NB), TPB, 0, stream>>>(x1h, w2r, c2b, y2, stats2, C2);
  k_gnfin<<<dim3(32, NB), 64, 0, stream>>>(stats2, g2g, g2b, scale2, shift2, C2, 8);
  k_build_vsoh<<<dim3(16, NB), TPB, 0, stream>>>(y2, scale2, shift2, vsoh);

  // all 4 projections (vsr, k, q, v) in one dispatch
  k_gemm_all<<<dim3(12, 8, NB), TPB, 0, stream>>>(vsoh, wcat, vsr, kb16, qb16, vtb16,
                                                  rb, kb, qb, vb, mod);

  // txt attention -> out channels [258, 558)
  k_txtattn<<<dim3(4, NB), TPB, 0, stream>>>(vsr, txt, out);

  // video self-attention (bf16 MFMA flash) -> out channels [0, 258)
  k_flash_mfma<<<dim3(512), 256, 0, stream>>>(kb16, qb16, vtb16, out);
}

// Round 11
// 374.556 us; speedup vs baseline: 1.0465x; 1.0465x over previous
//
#include <hip/hip_runtime.h>
#include <cstddef>

#define TPB 256

typedef unsigned short ushort_t;
typedef __attribute__((ext_vector_type(8))) short s8v;
typedef __attribute__((ext_vector_type(4))) float f4v;
typedef __attribute__((ext_vector_type(4))) unsigned u4v;

#define MFMA16(a, b, c) __builtin_amdgcn_mfma_f32_16x16x32_bf16((a), (b), (c), 0, 0, 0)

static const int NB   = 32;    // batch
static const int NPIX = 1024;  // 32x32
static const int CIN  = 264;
static const int C1   = 128;
static const int C2   = 256;
static const int VF_  = 258;
static const int DS_  = 300;
static const int LL   = 20;

__device__ __forceinline__ ushort_t f2b(float x) {
  unsigned u = __builtin_bit_cast(unsigned, x);
  u = (u + 0x7fffu + ((u >> 16) & 1u)) >> 16;
  return (ushort_t)u;
}

// ---------------- fused prep kernel ----------------
__global__ __launch_bounds__(TPB) void k_prep(
    const float* __restrict__ c1w, const float* __restrict__ c2w,
    const float* __restrict__ rw, const float* __restrict__ kw,
    const float* __restrict__ qw, const float* __restrict__ vw,
    const float* __restrict__ txt, const float* __restrict__ iw,
    const float* __restrict__ ib,
    const float* __restrict__ video, const float* __restrict__ spatial,
    ushort_t* __restrict__ w1r, ushort_t* __restrict__ w2r,
    ushort_t* __restrict__ wcat,
    float* __restrict__ mod, ushort_t* __restrict__ x0h) {
  int bid = blockIdx.x;
  const int tid = threadIdx.x;

  if (bid < 1296) {  // wreorder2 conv1
    int i = bid * TPB + tid;
    if (i < 9 * 9 * 128 * 32) {
      int j = i & 31;
      int oc = (i >> 5) % 128;
      int ts = (i >> 5) / 128;
      int s = ts % 9, t = ts / 9;
      int ic = s * 32 + j;
      float v = (ic < 264) ? c1w[((size_t)oc * 264 + ic) * 9 + t] : 0.f;
      w1r[i] = f2b(v);
    }
    return;
  }
  bid -= 1296;
  if (bid < 1152) {  // wreorder2 conv2
    int i = bid * TPB + tid;
    if (i < 9 * 4 * 256 * 32) {
      int j = i & 31;
      int oc = (i >> 5) % 256;
      int ts = (i >> 5) / 256;
      int s = ts % 4, t = ts / 4;
      int ic = s * 32 + j;
      float v = (ic < 128) ? c2w[((size_t)oc * 128 + ic) * 9 + t] : 0.f;
      w2r[i] = f2b(v);
    }
    return;
  }
  bid -= 1152;
  if (bid < 4 * 432) {  // wprep x4 -> wcat segments (0:rw 1:kw 2:qw 3:vw)
    int which = bid / 432;
    int i = (bid - which * 432) * TPB + tid;
    if (i < 384 * 288) {
      int n = i / 288, k = i - n * 288;
      const float* src = (which == 0) ? rw : (which == 1) ? kw : (which == 2) ? qw : vw;
      int N = (which == 0) ? 300 : 258;
      float v = (n < N && k < 258) ? src[(size_t)n * 258 + k] : 0.f;
      wcat[(size_t)which * 110592 + i] = f2b(v);
    }
    return;
  }
  bid -= 4 * 432;
  if (bid < 32) {  // tmaxmod, b = bid
    int b = bid;
    __shared__ float tm[DS_];
    for (int d = tid; d < DS_; d += TPB) {
      const float* p = txt + ((size_t)b * DS_ + d) * LL;
      float m = p[0];
      for (int l = 1; l < LL; ++l) m = fmaxf(m, p[l]);
      tm[d] = m;
    }
    __syncthreads();
    for (int oc = tid; oc < VF_; oc += TPB) {
      const float* wr = iw + (size_t)oc * DS_;
      float s = ib[oc];
      for (int d = 0; d < DS_; ++d) s += tm[d] * wr[d];
      mod[(size_t)b * VF_ + oc] = s;
    }
    return;
  }
  bid -= 32;
  {  // cat_nhwc
    const int pb = bid & 15;
    const int b = bid >> 4;
    __shared__ ushort_t lds[264][72];
    for (int u = tid; u < 264 * 64; u += TPB) {
      int c = u >> 6, px = u & 63;
      int p = (pb << 6) + px;
      float v = (c < 256) ? video[(((size_t)b * 256 + c) << 10) + p]
                          : spatial[(((size_t)b * 8 + (c - 256)) << 10) + p];
      lds[c][px] = f2b(v);
    }
    __syncthreads();
    for (int u = tid; u < 64 * 36; u += TPB) {
      int px = u / 36, ch = u - px * 36;
      s8v v;
#pragma unroll
      for (int j = 0; j < 8; ++j) {
        int ic = ch * 8 + j;
        v[j] = (ic < 264) ? (short)lds[ic][px] : (short)0;
      }
      *(s8v*)(x0h + ((size_t)((b << 10) + (pb << 6) + px)) * 288 + ch * 8) = v;
    }
  }
}

// ---------------- conv 3x3 via bf16 MFMA implicit GEMM (+GN stats) ----------------
template <int ICG>
__global__ __launch_bounds__(TPB) void k_conv_mfma(const ushort_t* __restrict__ in_h,
                                                   const ushort_t* __restrict__ wr,
                                                   const float* __restrict__ bias,
                                                   float* __restrict__ out,
                                                   float* __restrict__ stats, int Cout) {
  const int ICPAD = ICG * 8;
  const int NS = ICG / 4;
  const int ICGS = 4 * 34 * 8 + 24;
  const int b   = blockIdx.z;
  const int ocb = blockIdx.y << 7;
  const int pxb = blockIdx.x;
  const int tid = threadIdx.x;
  const int w = tid >> 6, lane = tid & 63;
  const int lhi = lane >> 4, llo = lane & 15;

  __shared__ ushort_t in_t[ICG * ICGS];

  for (int u = tid; u < ICG * 8; u += TPB) {
    int icg = u >> 3, rem = u & 7, row = rem >> 1, col = (rem & 1) ? 33 : 0;
    *(s8v*)&in_t[icg * ICGS + (row * 34 + col) * 8] = (s8v){0, 0, 0, 0, 0, 0, 0, 0};
  }
  for (int r = 0; r < 4; ++r) {
    int gy = (pxb << 1) - 1 + r;
    if ((unsigned)gy < 32u) {
      const ushort_t* src = in_h + ((size_t)((b << 10) + (gy << 5))) * ICPAD;
      for (int u = tid; u < 32 * ICG; u += TPB) {
        int px = u / ICG, icg = u - px * ICG;
        *(s8v*)&in_t[icg * ICGS + (r * 34 + px + 1) * 8] = *(const s8v*)(src + u * 8);
      }
    } else {
      for (int u = tid; u < 32 * ICG; u += TPB) {
        int px = u / ICG, icg = u - px * ICG;
        *(s8v*)&in_t[icg * ICGS + (r * 34 + px + 1) * 8] = (s8v){0, 0, 0, 0, 0, 0, 0, 0};
      }
    }
  }
  __syncthreads();

  f4v acc[2][4];
#pragma unroll
  for (int i = 0; i < 2; ++i)
#pragma unroll
    for (int m = 0; m < 4; ++m) acc[i][m] = (f4v){0.f, 0.f, 0.f, 0.f};

  for (int t = 0; t < 9; ++t) {
    const int ky = t / 3, kx = t - ky * 3;
#pragma unroll
    for (int s = 0; s < NS; ++s) {
      const ushort_t* wp = wr + (((size_t)(t * NS + s) * Cout + ocb + w * 32 + llo) << 5) + lhi * 8;
      s8v a0 = *(const s8v*)(wp);
      s8v a1 = *(const s8v*)(wp + (16 << 5));
      const int icg = (s << 2) + lhi;
#pragma unroll
      for (int m = 0; m < 4; ++m) {
        const int row = (m >> 1) + ky;
        const int col = ((m & 1) << 4) + llo + kx;
        s8v bm = *(const s8v*)&in_t[icg * ICGS + (row * 34 + col) * 8];
        acc[0][m] = MFMA16(a0, bm, acc[0][m]);
        acc[1][m] = MFMA16(a1, bm, acc[1][m]);
      }
    }
  }

#pragma unroll
  for (int i = 0; i < 2; ++i) {
#pragma unroll
    for (int r = 0; r < 4; ++r) {
      const int oc = ocb + w * 32 + i * 16 + lhi * 4 + r;
      const float bv = bias[oc];
      float sm = 0.f, sq = 0.f;
#pragma unroll
      for (int m = 0; m < 4; ++m) {
        const int px = (pxb << 6) + (m << 4) + llo;
        float v = acc[i][m][r] + bv;
        out[(((size_t)b * Cout + oc) << 10) + px] = v;
        sm += v;
        sq += v * v;
      }
#pragma unroll
      for (int off = 1; off < 16; off <<= 1) {
        sm += __shfl_xor(sm, off);
        sq += __shfl_xor(sq, off);
      }
      if (llo == 0) {
        size_t sidx = ((((size_t)b * Cout + oc) << 4) + pxb) << 1;
        stats[sidx] = sm;
        stats[sidx + 1] = sq;
      }
    }
  }
}

// ---------------- GN finalize ----------------
__global__ __launch_bounds__(64) void k_gnfin(const float* __restrict__ stats,
                                              const float* __restrict__ gamma,
                                              const float* __restrict__ beta,
                                              float* __restrict__ scale,
                                              float* __restrict__ shift,
                                              int C, int cpg) {
  const int g = blockIdx.x, b = blockIdx.y;
  const int n = cpg << 4;
  float s = 0.f, q = 0.f;
  for (int i = threadIdx.x; i < n; i += 64) {
    int c = g * cpg + (i >> 4), pxb = i & 15;
    size_t idx = ((((size_t)b * C + c) << 4) + pxb) << 1;
    s += stats[idx];
    q += stats[idx + 1];
  }
#pragma unroll
  for (int off = 32; off > 0; off >>= 1) {
    s += __shfl_xor(s, off);
    q += __shfl_xor(q, off);
  }
  const float M = (float)(cpg << 10);
  float mean = s / M;
  float rsig = rsqrtf(q / M - mean * mean + 1e-5f);
  if ((int)threadIdx.x < cpg) {
    int c = g * cpg + threadIdx.x;
    float sc = rsig * gamma[c];
    scale[(size_t)b * C + c] = sc;
    shift[(size_t)b * C + c] = beta[c] - mean * sc;
  }
}

// ---------------- c-major fp32 -> NHWC bf16 with fused GN+ReLU ----------------
__global__ __launch_bounds__(TPB) void k_to_nhwc128(const float* __restrict__ src,
                                                    const float* __restrict__ scale,
                                                    const float* __restrict__ shift,
                                                    ushort_t* __restrict__ dst) {
  const int pb = blockIdx.x;
  const int b  = blockIdx.y;
  const int tid = threadIdx.x;
  __shared__ ushort_t lds[128][72];
  for (int u = tid; u < 128 * 64; u += TPB) {
    int c = u >> 6, px = u & 63;
    int p = (pb << 6) + px;
    float v = src[(((size_t)b * 128 + c) << 10) + p];
    v = fmaxf(v * scale[(size_t)b * 128 + c] + shift[(size_t)b * 128 + c], 0.f);
    lds[c][px] = f2b(v);
  }
  __syncthreads();
  for (int u = tid; u < 64 * 16; u += TPB) {
    int px = u >> 4, ch = u & 15;
    s8v v;
#pragma unroll
    for (int j = 0; j < 8; ++j) v[j] = (short)lds[ch * 8 + j][px];
    *(s8v*)(dst + ((size_t)((b << 10) + (pb << 6) + px)) * 128 + ch * 8) = v;
  }
}

// y2 + fused GN+ReLU + coords -> vso_h bf16 [b][1024][288]
__global__ __launch_bounds__(TPB) void k_build_vsoh(const float* __restrict__ y2,
                                                    const float* __restrict__ scale,
                                                    const float* __restrict__ shift,
                                                    ushort_t* __restrict__ dst) {
  const int pb = blockIdx.x;
  const int b  = blockIdx.y;
  const int tid = threadIdx.x;
  __shared__ ushort_t lds[256][72];
  for (int u = tid; u < 256 * 64; u += TPB) {
    int c = u >> 6, px = u & 63;
    int p = (pb << 6) + px;
    float v = y2[(((size_t)b * 256 + c) << 10) + p];
    v = fmaxf(v * scale[(size_t)b * 256 + c] + shift[(size_t)b * 256 + c], 0.f);
    lds[c][px] = f2b(v);
  }
  __syncthreads();
  for (int u = tid; u < 64 * 36; u += TPB) {
    int px = u / 36, ch = u - px * 36;
    int p = (pb << 6) + px;
    s8v v;
#pragma unroll
    for (int j = 0; j < 8; ++j) {
      int cg = ch * 8 + j;
      float fv;
      if (cg < 256)      { v[j] = (short)lds[cg][px]; continue; }
      else if (cg == 256) fv = -1.f + (2.f / 31.f) * (float)(p & 31);
      else if (cg == 257) fv = -1.f + (2.f / 31.f) * (float)(p >> 5);
      else                fv = 0.f;
      v[j] = (short)f2b(fv);
    }
    *(s8v*)(dst + ((size_t)((b << 10) + p)) * 288 + ch * 8) = v;
  }
}

// ---------------- bf16 MFMA GEMM (separate dispatch per projection) ----------------
// grid: 1D 768 blocks, XCD-swizzled: all 24 tiles of a batch on one XCD.
// MODE 1: bf16 out [b][1024][288], *mod    (k, q)
// MODE 2: bf16 out chunk-blocked Vt [b][32][272][32]  (v)
// MODE 3: fp32 out transposed [b][300][1024]          (vsr)
template <int MODE>
__global__ __launch_bounds__(TPB) void k_gemm_mfma(const ushort_t* __restrict__ A,
                                                   const ushort_t* __restrict__ Bw,
                                                   void* __restrict__ Cout,
                                                   const float* __restrict__ bias,
                                                   const float* __restrict__ mod) {
  const int wg = blockIdx.x;            // 0..767
  const int xcd = wg & 7;
  const int s2 = wg >> 3;               // 0..95
  const int b = xcd * 4 + (s2 / 24);
  const int rem = s2 - (s2 / 24) * 24;  // 0..23
  const int n0 = (rem % 3) << 7;
  const int m0 = (rem / 3) << 7;
  const int tid = threadIdx.x;
  const int w = tid >> 6, lane = tid & 63;
  const int wr = w >> 1, wc = w & 1;
  const int lhi = lane >> 4, llo = lane & 15;

  __shared__ ushort_t A_l[128][40];
  __shared__ ushort_t B_l[128][40];

  f4v acc[4][4];
#pragma unroll
  for (int i = 0; i < 4; ++i)
#pragma unroll
    for (int j = 0; j < 4; ++j) acc[i][j] = (f4v){0.f, 0.f, 0.f, 0.f};

  const ushort_t* Ab = A + (((size_t)b << 10)) * 288;

  for (int k0 = 0; k0 < 288; k0 += 32) {
    for (int u = tid; u < 512; u += TPB) {
      int row = u >> 2, seg = u & 3;
      *(s8v*)&A_l[row][seg * 8] = *(const s8v*)(Ab + (size_t)(m0 + row) * 288 + k0 + seg * 8);
      *(s8v*)&B_l[row][seg * 8] = *(const s8v*)(Bw + (size_t)(n0 + row) * 288 + k0 + seg * 8);
    }
    __syncthreads();
    s8v am[4], bn[4];
#pragma unroll
    for (int i = 0; i < 4; ++i) am[i] = *(const s8v*)&A_l[wr * 64 + i * 16 + llo][lhi * 8];
#pragma unroll
    for (int j = 0; j < 4; ++j) bn[j] = *(const s8v*)&B_l[wc * 64 + j * 16 + llo][lhi * 8];
#pragma unroll
    for (int i = 0; i < 4; ++i)
#pragma unroll
      for (int j = 0; j < 4; ++j) {
        if (MODE >= 2) acc[i][j] = MFMA16(bn[j], am[i], acc[i][j]);
        else           acc[i][j] = MFMA16(am[i], bn[j], acc[i][j]);
      }
    __syncthreads();
  }

  if (MODE == 1) {
    ushort_t* Cb = (ushort_t*)Cout + (size_t)b * 1024 * 288;
#pragma unroll
    for (int j = 0; j < 4; ++j) {
      int n = n0 + wc * 64 + j * 16 + llo;
      if (n >= 288) continue;
      bool real = n < VF_;
      float bv = real ? bias[n] : 0.f;
      float sm = real ? mod[(size_t)b * VF_ + n] : 0.f;
#pragma unroll
      for (int i = 0; i < 4; ++i)
#pragma unroll
        for (int r = 0; r < 4; ++r) {
          int m = m0 + wr * 64 + i * 16 + lhi * 4 + r;
          Cb[(size_t)m * 288 + n] = f2b(real ? (acc[i][j][r] + bv) * sm : 0.f);
        }
    }
  } else if (MODE == 2) {
    // chunk-blocked transposed store: Vt_blk[b][m>>5][n][m&31]
    ushort_t* Cb = (ushort_t*)Cout + (size_t)b * 32 * 272 * 32;
#pragma unroll
    for (int j = 0; j < 4; ++j)
#pragma unroll
      for (int r = 0; r < 4; ++r) {
        int n = n0 + wc * 64 + j * 16 + lhi * 4 + r;
        if (n >= 272) continue;
        bool real = n < VF_;
        float bv = real ? bias[n] : 0.f;
#pragma unroll
        for (int i = 0; i < 4; ++i) {
          int m = m0 + wr * 64 + i * 16 + llo;
          int mc = m >> 5, mlo = m & 31;
          Cb[(((size_t)mc * 272 + n) << 5) + mlo] = f2b(real ? acc[i][j][r] + bv : 0.f);
        }
      }
  } else {
    // MODE 3: fp32 transposed [300][1024]
    float* Cf = (float*)Cout + (size_t)b * 300 * 1024;
#pragma unroll
    for (int j = 0; j < 4; ++j)
#pragma unroll
      for (int r = 0; r < 4; ++r) {
        int n = n0 + wc * 64 + j * 16 + lhi * 4 + r;
        if (n >= 300) continue;
        float bv = bias[n];
#pragma unroll
        for (int i = 0; i < 4; ++i) {
          int m = m0 + wr * 64 + i * 16 + llo;
          Cf[((size_t)n << 10) + m] = acc[i][j][r] + bv;
        }
      }
  }
}

// ---------------- txt cross-attention (vsr transposed [b][300][1024]) ----------------
__global__ __launch_bounds__(TPB) void k_txtattn(const float* __restrict__ vsrT,
                                                 const float* __restrict__ txt,
                                                 float* __restrict__ out) {
  const int b = blockIdx.y;
  const int p = blockIdx.x * TPB + threadIdx.x;
  __shared__ float tl[DS_ * LL];
  for (int i = threadIdx.x; i < DS_ * LL; i += TPB) tl[i] = txt[(size_t)b * DS_ * LL + i];
  __syncthreads();
  const float* vr = vsrT + ((size_t)b * DS_ << 10) + p;
  float lg[LL];
#pragma unroll
  for (int l = 0; l < LL; ++l) lg[l] = 0.f;
  for (int d = 0; d < DS_; d += 4) {
    float v0 = vr[(size_t)(d + 0) << 10];
    float v1 = vr[(size_t)(d + 1) << 10];
    float v2 = vr[(size_t)(d + 2) << 10];
    float v3 = vr[(size_t)(d + 3) << 10];
    const float* tr = tl + d * LL;
#pragma unroll
    for (int l = 0; l < LL; ++l)
      lg[l] += v0 * tr[l] + v1 * tr[l + 20] + v2 * tr[l + 40] + v3 * tr[l + 60];
  }
  const float sc = 0.057735026919f;
  float mx = lg[0] * sc;
#pragma unroll
  for (int l = 1; l < LL; ++l) mx = fmaxf(mx, lg[l] * sc);
  float sum = 0.f;
#pragma unroll
  for (int l = 0; l < LL; ++l) {
    lg[l] = __expf(lg[l] * sc - mx);
    sum += lg[l];
  }
  float inv = 1.f / sum;
#pragma unroll
  for (int l = 0; l < LL; ++l) lg[l] *= inv;
  float* ob = out + (((size_t)b * 558 + VF_) << 10) + p;
  for (int d = 0; d < DS_; ++d) {
    const float* tr = tl + d * LL;
    float s = 0.f;
#pragma unroll
    for (int l = 0; l < LL; ++l) s += lg[l] * tr[l];
    ob[(size_t)d << 10] = s;
  }
}

// ---------------- video self-attention: bf16 MFMA flash v3 ----------------
// K,Q: bf16 [b][1024][288]. Vt_blk: bf16 [b][32][272][32].
// Q in LDS as fragment-contiguous blocks (conflict-free b128); V direct from L2.
__global__ __launch_bounds__(256, 2) void k_flash_mfma(const ushort_t* __restrict__ Kb,
                                                       const ushort_t* __restrict__ Qb,
                                                       const ushort_t* __restrict__ Vtb,
                                                       float* __restrict__ out) {
  const int wg = blockIdx.x;           // 0..511
  const int xcd = wg & 7, s = wg >> 3;
  const int b = xcd * 4 + (s >> 4);
  const int n0 = (s & 15) << 6;
  const int tid = threadIdx.x;
  const int w = tid >> 6, lane = tid & 63;
  const int lhi = lane >> 4;
  const int llo = lane & 15;

  // q_blk[ks][row 0..31][32 elems], per-ks stride 1032 elems (8-elem rotation pad)
  __shared__ ushort_t q_l[9 * 1032];

  s8v kf[9];
  {
    const ushort_t* kp = Kb + ((size_t)(b * 1024 + n0 + w * 16 + llo)) * 288 + lhi * 8;
#pragma unroll
    for (int ks = 0; ks < 9; ++ks) kf[ks] = *(const s8v*)(kp + ks * 32);
  }

  const ushort_t* Qbase = Qb + (((size_t)b << 10)) * 288;
  const ushort_t* Vbase = Vtb + (size_t)b * 32 * 272 * 32;

  s8v qs[5];
  auto ISSUE = [&](int mc) {
#pragma unroll
    for (int i = 0; i < 5; ++i) {
      int u = tid + (i << 8);
      if (u < 1152) qs[i] = *(const s8v*)(Qbase + (size_t)((mc << 5) + u / 36) * 288 + (u % 36) * 8);
    }
  };
  auto WRITE = [&]() {
#pragma unroll
    for (int i = 0; i < 5; ++i) {
      int u = tid + (i << 8);
      if (u < 1152) {
        int r = u / 36, cq = u - r * 36;
        *(s8v*)&q_l[(cq >> 2) * 1032 + (r << 5) + ((cq & 3) << 3)] = qs[i];
      }
    }
  };

  f4v oacc[17];
#pragma unroll
  for (int i = 0; i < 17; ++i) oacc[i] = (f4v){0.f, 0.f, 0.f, 0.f};
  float mreg = -1e30f, lreg = 0.f;  // per-lane column n = n0 + w*16 + llo

  const float sc = 0.0622572819f;  // 1/sqrt(258)
  const int srcA = llo + ((lhi & 1) << 5);
  const int srcB = srcA + 16;
  const bool hi2 = lhi >= 2;
  const int qoff = (llo << 5) + (lhi << 3);  // lane offset within a q fragment block

  ISSUE(0);
  WRITE();
  __syncthreads();
  ISSUE(1);

  for (int mc = 0; mc < 32; ++mc) {
    const ushort_t* Vc = Vbase + (size_t)mc * 8704 + qoff;  // same (llo,lhi) tiling

    // V prefetch group A (consumed in PV dt 0..8)
    s8v va[9];
#pragma unroll
    for (int dt = 0; dt < 9; ++dt) va[dt] = *(const s8v*)(Vc + (dt << 9));

    // S^T[m][n] via swapped QK^T
    f4v sacc0 = {0.f, 0.f, 0.f, 0.f}, sacc1 = {0.f, 0.f, 0.f, 0.f};
    __builtin_amdgcn_s_setprio(1);
#pragma unroll
    for (int ks = 0; ks < 9; ++ks) {
      s8v q0 = *(const s8v*)&q_l[ks * 1032 + qoff];
      s8v q1 = *(const s8v*)&q_l[ks * 1032 + 512 + qoff];
      sacc0 = MFMA16(q0, kf[ks], sacc0);
      sacc1 = MFMA16(q1, kf[ks], sacc1);
    }
    __builtin_amdgcn_s_setprio(0);

    // V prefetch group B (consumed in PV dt 9..16)
    s8v vb[8];
#pragma unroll
    for (int dt = 0; dt < 8; ++dt) vb[dt] = *(const s8v*)(Vc + ((dt + 9) << 9));

    // lane-local online softmax
    float pmax = fmaxf(fmaxf(fmaxf(sacc0[0], sacc0[1]), fmaxf(sacc0[2], sacc0[3])),
                       fmaxf(fmaxf(sacc1[0], sacc1[1]), fmaxf(sacc1[2], sacc1[3])));
    pmax = fmaxf(pmax, __shfl_xor(pmax, 16));
    pmax = fmaxf(pmax, __shfl_xor(pmax, 32));
    float mn = fmaxf(mreg, pmax * sc);
    float alpha = __expf(mreg - mn);
    mreg = mn;

    float p0[4], p1[4];
    float rsum = 0.f;
#pragma unroll
    for (int r = 0; r < 4; ++r) {
      p0[r] = __expf(sacc0[r] * sc - mn);
      p1[r] = __expf(sacc1[r] * sc - mn);
      rsum += p0[r] + p1[r];
    }
    rsum += __shfl_xor(rsum, 16);
    rsum += __shfl_xor(rsum, 32);
    lreg = lreg * alpha + rsum;

    // pack P -> bf16 PV B-fragment
    unsigned u0, u1, u2, u3;
    asm("v_cvt_pk_bf16_f32 %0, %1, %2" : "=v"(u0) : "v"(p0[0]), "v"(p0[1]));
    asm("v_cvt_pk_bf16_f32 %0, %1, %2" : "=v"(u1) : "v"(p0[2]), "v"(p0[3]));
    asm("v_cvt_pk_bf16_f32 %0, %1, %2" : "=v"(u2) : "v"(p1[0]), "v"(p1[1]));
    asm("v_cvt_pk_bf16_f32 %0, %1, %2" : "=v"(u3) : "v"(p1[2]), "v"(p1[3]));
    unsigned s0a = __shfl(u0, srcA, 64), s2a = __shfl(u2, srcA, 64);
    unsigned s1a = __shfl(u1, srcA, 64), s3a = __shfl(u3, srcA, 64);
    unsigned s0b = __shfl(u0, srcB, 64), s2b = __shfl(u2, srcB, 64);
    unsigned s1b = __shfl(u1, srcB, 64), s3b = __shfl(u3, srcB, 64);
    u4v pu;
    pu[0] = hi2 ? s2a : s0a;
    pu[1] = hi2 ? s3a : s1a;
    pu[2] = hi2 ? s2b : s0b;
    pu[3] = hi2 ? s3b : s1b;
    s8v pf = __builtin_bit_cast(s8v, pu);

    // PV: O^T[d][n] += Vt_frag * P
    __builtin_amdgcn_s_setprio(1);
#pragma unroll
    for (int dt = 0; dt < 17; ++dt) {
      s8v vf = (dt < 9) ? va[dt] : vb[dt - 9];
      f4v o = oacc[dt];
      o[0] *= alpha; o[1] *= alpha; o[2] *= alpha; o[3] *= alpha;
      oacc[dt] = MFMA16(vf, pf, o);
    }
    __builtin_amdgcn_s_setprio(0);

    __syncthreads();  // all waves done reading q_l chunk mc
    if (mc < 31) {
      WRITE();        // chunk mc+1 -> LDS
      __syncthreads();
      if (mc < 30) ISSUE(mc + 2);
    }
  }

  // epilogue
  float linv = 1.f / lreg;
  const int n = n0 + w * 16 + llo;
#pragma unroll
  for (int dt = 0; dt < 17; ++dt) {
#pragma unroll
    for (int r = 0; r < 4; ++r) {
      int d = dt * 16 + lhi * 4 + r;
      if (d < VF_) out[((size_t)(b * 558 + d) << 10) + n] = oacc[dt][r] * linv;
    }
  }
}

// ---------------- launcher ----------------
extern "C" void kernel_launch(void* const* d_in, const int* in_sizes, int n_in,
                              void* d_out, int out_size, void* d_ws, size_t ws_size,
                              hipStream_t stream) {
  const float* spatial = (const float*)d_in[0];
  const float* video   = (const float*)d_in[1];
  const float* txt     = (const float*)d_in[2];
  const float* c1w = (const float*)d_in[3];
  const float* c1b = (const float*)d_in[4];
  const float* g1g = (const float*)d_in[5];
  const float* g1b = (const float*)d_in[6];
  const float* c2w = (const float*)d_in[7];
  const float* c2b = (const float*)d_in[8];
  const float* g2g = (const float*)d_in[9];
  const float* g2b = (const float*)d_in[10];
  const float* rw  = (const float*)d_in[11];
  const float* rb  = (const float*)d_in[12];
  const float* kw  = (const float*)d_in[13];
  const float* kb  = (const float*)d_in[14];
  const float* qw  = (const float*)d_in[15];
  const float* qb  = (const float*)d_in[16];
  const float* vw  = (const float*)d_in[17];
  const float* vb  = (const float*)d_in[18];
  const float* iw  = (const float*)d_in[19];
  const float* ib  = (const float*)d_in[20];
  float* out = (float*)d_out;
  float* ws = (float*)d_ws;

  // ws layout (float offsets), lifetime-aliased
  ushort_t* x0h    = (ushort_t*)(ws + 0);          // [0, 4.72M) -> conv1
  float*    vsr    = ws + 0;                       // [0, 9.83M)  (transposed [300][1024]) after x1h dead
  float*    y1     = ws + 5000000;                 // [5.0M, 9.2M)
  ushort_t* x1h    = (ushort_t*)(ws + 9300000);    // [9.3M, 11.4M)
  ushort_t* kb16   = (ushort_t*)(ws + 10000000);   // [10.0M, 14.72M)  after x1h dead
  float*    y2     = ws + 11500000;                // [11.5M, 19.9M)
  ushort_t* qb16   = (ushort_t*)(ws + 14800000);   // [14.8M, 19.52M)  after y2 dead
  ushort_t* vsoh   = (ushort_t*)(ws + 20000000);   // [20.0M, 24.72M)
  ushort_t* vtb16  = (ushort_t*)(ws + 24800000);   // [24.8M, 29.26M)
  ushort_t* wcat   = (ushort_t*)(ws + 29300000);   // 4*110592 us
  ushort_t* w1r    = (ushort_t*)(ws + 29540000);
  ushort_t* w2r    = (ushort_t*)(ws + 29710000);
  float*    mod    = ws + 29860000;                // 8,256
  float*    stats1 = ws + 29900000;                // 131,072
  float*    stats2 = ws + 30100000;                // 262,144
  float*    scale1 = ws + 30400000;                // 4,096
  float*    shift1 = ws + 30410000;                // 4,096
  float*    scale2 = ws + 30420000;                // 8,192
  float*    shift2 = ws + 30430000;                // 8,192

  // all prep (weights, mod, concat) in one dispatch
  k_prep<<<dim3(4720), TPB, 0, stream>>>(c1w, c2w, rw, kw, qw, vw, txt, iw, ib,
                                         video, spatial,
                                         w1r, w2r, wcat, mod, x0h);

  // conv1 (MFMA + GN stats); finalize; transpose+GN+relu -> x1h
  k_conv_mfma<36><<<dim3(16, 1, NB), TPB, 0, stream>>>(x0h, w1r, c1b, y1, stats1, C1);
  k_gnfin<<<dim3(32, NB), 64, 0, stream>>>(stats1, g1g, g1b, scale1, shift1, C1, 4);
  k_to_nhwc128<<<dim3(16, NB), TPB, 0, stream>>>(y1, scale1, shift1, x1h);

  // conv2 (MFMA + GN stats); finalize; vsoh (GN+relu+coords)
  k_conv_mfma<16><<<dim3(16, 2, NB), TPB, 0, stream>>>(x1h, w2r, c2b, y2, stats2, C2);
  k_gnfin<<<dim3(32, NB), 64, 0, stream>>>(stats2, g2g, g2b, scale2, shift2, C2, 8);
  k_build_vsoh<<<dim3(16, NB), TPB, 0, stream>>>(y2, scale2, shift2, vsoh);

  // 4 projections, separate template dispatches, XCD-swizzled 1D grid
  k_gemm_mfma<3><<<dim3(768), TPB, 0, stream>>>(vsoh, wcat + 0 * 110592, (void*)vsr, rb, nullptr);
  k_gemm_mfma<1><<<dim3(768), TPB, 0, stream>>>(vsoh, wcat + 1 * 110592, (void*)kb16, kb, mod);
  k_gemm_mfma<1><<<dim3(768), TPB, 0, stream>>>(vsoh, wcat + 2 * 110592, (void*)qb16, qb, mod);
  k_gemm_mfma<2><<<dim3(768), TPB, 0, stream>>>(vsoh, wcat + 3 * 110592, (void*)vtb16, vb, nullptr);

  // txt attention -> out channels [258, 558)
  k_txtattn<<<dim3(4, NB), TPB, 0, stream>>>(vsr, txt, out);

  // video self-attention (bf16 MFMA flash) -> out channels [0, 258)
  k_flash_mfma<<<dim3(512), 256, 0, stream>>>(kb16, qb16, vtb16, out);
}

// Round 12
// 350.704 us; speedup vs baseline: 1.1176x; 1.0680x over previous
//
#include <hip/hip_runtime.h>
#include <cstddef>

#define TPB 256

typedef unsigned short ushort_t;
typedef __attribute__((ext_vector_type(8))) short s8v;
typedef __attribute__((ext_vector_type(4))) float f4v;
typedef __attribute__((ext_vector_type(4))) unsigned u4v;

#define MFMA16(a, b, c) __builtin_amdgcn_mfma_f32_16x16x32_bf16((a), (b), (c), 0, 0, 0)

static const int NB   = 32;    // batch
static const int NPIX = 1024;  // 32x32
static const int CIN  = 264;
static const int C1   = 128;
static const int C2   = 256;
static const int VF_  = 258;
static const int DS_  = 300;
static const int LL   = 20;

__device__ __forceinline__ ushort_t f2b(float x) {
  unsigned u = __builtin_bit_cast(unsigned, x);
  u = (u + 0x7fffu + ((u >> 16) & 1u)) >> 16;
  return (ushort_t)u;
}
__device__ __forceinline__ float b2f(ushort_t h) {
  unsigned u = ((unsigned)h) << 16;
  return __builtin_bit_cast(float, u);
}

// ---------------- fused prep kernel ----------------
__global__ __launch_bounds__(TPB) void k_prep(
    const float* __restrict__ c1w, const float* __restrict__ c2w,
    const float* __restrict__ rw, const float* __restrict__ kw,
    const float* __restrict__ qw, const float* __restrict__ vw,
    const float* __restrict__ txt, const float* __restrict__ iw,
    const float* __restrict__ ib,
    const float* __restrict__ video, const float* __restrict__ spatial,
    ushort_t* __restrict__ w1r, ushort_t* __restrict__ w2r,
    ushort_t* __restrict__ wcat,
    float* __restrict__ mod, ushort_t* __restrict__ x0h) {
  int bid = blockIdx.x;
  const int tid = threadIdx.x;

  if (bid < 1296) {  // wreorder2 conv1
    int i = bid * TPB + tid;
    if (i < 9 * 9 * 128 * 32) {
      int j = i & 31;
      int oc = (i >> 5) % 128;
      int ts = (i >> 5) / 128;
      int s = ts % 9, t = ts / 9;
      int ic = s * 32 + j;
      float v = (ic < 264) ? c1w[((size_t)oc * 264 + ic) * 9 + t] : 0.f;
      w1r[i] = f2b(v);
    }
    return;
  }
  bid -= 1296;
  if (bid < 1152) {  // wreorder2 conv2
    int i = bid * TPB + tid;
    if (i < 9 * 4 * 256 * 32) {
      int j = i & 31;
      int oc = (i >> 5) % 256;
      int ts = (i >> 5) / 256;
      int s = ts % 4, t = ts / 4;
      int ic = s * 32 + j;
      float v = (ic < 128) ? c2w[((size_t)oc * 128 + ic) * 9 + t] : 0.f;
      w2r[i] = f2b(v);
    }
    return;
  }
  bid -= 1152;
  if (bid < 4 * 432) {  // wprep x4 -> wcat segments (0:rw 1:kw 2:qw 3:vw)
    int which = bid / 432;
    int i = (bid - which * 432) * TPB + tid;
    if (i < 384 * 288) {
      int n = i / 288, k = i - n * 288;
      const float* src = (which == 0) ? rw : (which == 1) ? kw : (which == 2) ? qw : vw;
      int N = (which == 0) ? 300 : 258;
      float v = (n < N && k < 258) ? src[(size_t)n * 258 + k] : 0.f;
      wcat[(size_t)which * 110592 + i] = f2b(v);
    }
    return;
  }
  bid -= 4 * 432;
  if (bid < 32) {  // tmaxmod, b = bid
    int b = bid;
    __shared__ float tm[DS_];
    for (int d = tid; d < DS_; d += TPB) {
      const float* p = txt + ((size_t)b * DS_ + d) * LL;
      float m = p[0];
      for (int l = 1; l < LL; ++l) m = fmaxf(m, p[l]);
      tm[d] = m;
    }
    __syncthreads();
    for (int oc = tid; oc < VF_; oc += TPB) {
      const float* wr = iw + (size_t)oc * DS_;
      float s = ib[oc];
      for (int d = 0; d < DS_; ++d) s += tm[d] * wr[d];
      mod[(size_t)b * VF_ + oc] = s;
    }
    return;
  }
  bid -= 32;
  {  // cat_nhwc
    const int pb = bid & 15;
    const int b = bid >> 4;
    __shared__ ushort_t lds[264][72];
    for (int u = tid; u < 264 * 64; u += TPB) {
      int c = u >> 6, px = u & 63;
      int p = (pb << 6) + px;
      float v = (c < 256) ? video[(((size_t)b * 256 + c) << 10) + p]
                          : spatial[(((size_t)b * 8 + (c - 256)) << 10) + p];
      lds[c][px] = f2b(v);
    }
    __syncthreads();
    for (int u = tid; u < 64 * 36; u += TPB) {
      int px = u / 36, ch = u - px * 36;
      s8v v;
#pragma unroll
      for (int j = 0; j < 8; ++j) {
        int ic = ch * 8 + j;
        v[j] = (ic < 264) ? (short)lds[ic][px] : (short)0;
      }
      *(s8v*)(x0h + ((size_t)((b << 10) + (pb << 6) + px)) * 288 + ch * 8) = v;
    }
  }
}

// ---------------- conv 3x3 via bf16 MFMA implicit GEMM (+GN stats) ----------------
// OM 0: fp32 c-major out.  OM 1: raw bf16 NHWC out (LDS transpose in epilogue).
template <int ICG, int OM>
__global__ __launch_bounds__(TPB) void k_conv_mfma(const ushort_t* __restrict__ in_h,
                                                   const ushort_t* __restrict__ wr,
                                                   const float* __restrict__ bias,
                                                   void* __restrict__ outp,
                                                   float* __restrict__ stats, int Cout) {
  const int ICPAD = ICG * 8;
  const int NS = ICG / 4;
  const int ICGS = 4 * 34 * 8 + 24;
  const int b   = blockIdx.z;
  const int ocb = blockIdx.y << 7;
  const int pxb = blockIdx.x;
  const int tid = threadIdx.x;
  const int w = tid >> 6, lane = tid & 63;
  const int lhi = lane >> 4, llo = lane & 15;

  __shared__ ushort_t in_t[ICG * ICGS];

  for (int u = tid; u < ICG * 8; u += TPB) {
    int icg = u >> 3, rem = u & 7, row = rem >> 1, col = (rem & 1) ? 33 : 0;
    *(s8v*)&in_t[icg * ICGS + (row * 34 + col) * 8] = (s8v){0, 0, 0, 0, 0, 0, 0, 0};
  }
  for (int r = 0; r < 4; ++r) {
    int gy = (pxb << 1) - 1 + r;
    if ((unsigned)gy < 32u) {
      const ushort_t* src = in_h + ((size_t)((b << 10) + (gy << 5))) * ICPAD;
      for (int u = tid; u < 32 * ICG; u += TPB) {
        int px = u / ICG, icg = u - px * ICG;
        *(s8v*)&in_t[icg * ICGS + (r * 34 + px + 1) * 8] = *(const s8v*)(src + u * 8);
      }
    } else {
      for (int u = tid; u < 32 * ICG; u += TPB) {
        int px = u / ICG, icg = u - px * ICG;
        *(s8v*)&in_t[icg * ICGS + (r * 34 + px + 1) * 8] = (s8v){0, 0, 0, 0, 0, 0, 0, 0};
      }
    }
  }
  __syncthreads();

  f4v acc[2][4];
#pragma unroll
  for (int i = 0; i < 2; ++i)
#pragma unroll
    for (int m = 0; m < 4; ++m) acc[i][m] = (f4v){0.f, 0.f, 0.f, 0.f};

  for (int t = 0; t < 9; ++t) {
    const int ky = t / 3, kx = t - ky * 3;
#pragma unroll
    for (int s = 0; s < NS; ++s) {
      const ushort_t* wp = wr + (((size_t)(t * NS + s) * Cout + ocb + w * 32 + llo) << 5) + lhi * 8;
      s8v a0 = *(const s8v*)(wp);
      s8v a1 = *(const s8v*)(wp + (16 << 5));
      const int icg = (s << 2) + lhi;
#pragma unroll
      for (int m = 0; m < 4; ++m) {
        const int row = (m >> 1) + ky;
        const int col = ((m & 1) << 4) + llo + kx;
        s8v bm = *(const s8v*)&in_t[icg * ICGS + (row * 34 + col) * 8];
        acc[0][m] = MFMA16(a0, bm, acc[0][m]);
        acc[1][m] = MFMA16(a1, bm, acc[1][m]);
      }
    }
  }

  if (OM == 1) __syncthreads();  // in_t about to be reused as transpose buffer
  ushort_t* tb = in_t;           // [64 px][136] bf16 (OM==1 only)

#pragma unroll
  for (int i = 0; i < 2; ++i) {
#pragma unroll
    for (int r = 0; r < 4; ++r) {
      const int oc = ocb + w * 32 + i * 16 + lhi * 4 + r;
      const float bv = bias[oc];
      float sm = 0.f, sq = 0.f;
#pragma unroll
      for (int m = 0; m < 4; ++m) {
        const int px = (pxb << 6) + (m << 4) + llo;
        float v = acc[i][m][r] + bv;
        if (OM == 0) ((float*)outp)[(((size_t)b * Cout + oc) << 10) + px] = v;
        else         tb[((m << 4) + llo) * 136 + (w * 32 + i * 16 + lhi * 4 + r)] = f2b(v);
        sm += v;
        sq += v * v;
      }
#pragma unroll
      for (int off = 1; off < 16; off <<= 1) {
        sm += __shfl_xor(sm, off);
        sq += __shfl_xor(sq, off);
      }
      if (llo == 0) {
        size_t sidx = ((((size_t)b * Cout + oc) << 4) + pxb) << 1;
        stats[sidx] = sm;
        stats[sidx + 1] = sq;
      }
    }
  }

  if (OM == 1) {
    __syncthreads();
    ushort_t* dst = (ushort_t*)outp;
    for (int u = tid; u < 64 * 16; u += TPB) {
      int px = u >> 4, ch = u & 15;
      s8v val = *(const s8v*)&tb[px * 136 + ch * 8];
      *(s8v*)&dst[((size_t)((b << 10) + (pxb << 6) + px)) * Cout + ocb + ch * 8] = val;
    }
  }
}

// ---------------- GN finalize ----------------
__global__ __launch_bounds__(64) void k_gnfin(const float* __restrict__ stats,
                                              const float* __restrict__ gamma,
                                              const float* __restrict__ beta,
                                              float* __restrict__ scale,
                                              float* __restrict__ shift,
                                              int C, int cpg) {
  const int g = blockIdx.x, b = blockIdx.y;
  const int n = cpg << 4;
  float s = 0.f, q = 0.f;
  for (int i = threadIdx.x; i < n; i += 64) {
    int c = g * cpg + (i >> 4), pxb = i & 15;
    size_t idx = ((((size_t)b * C + c) << 4) + pxb) << 1;
    s += stats[idx];
    q += stats[idx + 1];
  }
#pragma unroll
  for (int off = 32; off > 0; off >>= 1) {
    s += __shfl_xor(s, off);
    q += __shfl_xor(q, off);
  }
  const float M = (float)(cpg << 10);
  float mean = s / M;
  float rsig = rsqrtf(q / M - mean * mean + 1e-5f);
  if ((int)threadIdx.x < cpg) {
    int c = g * cpg + threadIdx.x;
    float sc = rsig * gamma[c];
    scale[(size_t)b * C + c] = sc;
    shift[(size_t)b * C + c] = beta[c] - mean * sc;
  }
}

// ---------------- c-major fp32 -> NHWC bf16 with fused GN+ReLU (conv1) ----------------
__global__ __launch_bounds__(TPB) void k_to_nhwc128(const float* __restrict__ src,
                                                    const float* __restrict__ scale,
                                                    const float* __restrict__ shift,
                                                    ushort_t* __restrict__ dst) {
  const int pb = blockIdx.x;
  const int b  = blockIdx.y;
  const int tid = threadIdx.x;
  __shared__ ushort_t lds[128][72];
  for (int u = tid; u < 128 * 64; u += TPB) {
    int c = u >> 6, px = u & 63;
    int p = (pb << 6) + px;
    float v = src[(((size_t)b * 128 + c) << 10) + p];
    v = fmaxf(v * scale[(size_t)b * 128 + c] + shift[(size_t)b * 128 + c], 0.f);
    lds[c][px] = f2b(v);
  }
  __syncthreads();
  for (int u = tid; u < 64 * 16; u += TPB) {
    int px = u >> 4, ch = u & 15;
    s8v v;
#pragma unroll
    for (int j = 0; j < 8; ++j) v[j] = (short)lds[ch * 8 + j][px];
    *(s8v*)(dst + ((size_t)((b << 10) + (pb << 6) + px)) * 128 + ch * 8) = v;
  }
}

// x2raw NHWC bf16 + GN(scale/shift)+relu + coords -> vso_h bf16 [b][1024][288]
__global__ __launch_bounds__(TPB) void k_build_vsoh(const ushort_t* __restrict__ x2raw,
                                                    const float* __restrict__ scale,
                                                    const float* __restrict__ shift,
                                                    ushort_t* __restrict__ dst) {
  const int pb = blockIdx.x;
  const int b  = blockIdx.y;
  const int tid = threadIdx.x;
  __shared__ float sc_l[256], sh_l[256];
  for (int i = tid; i < 256; i += TPB) {
    sc_l[i] = scale[(size_t)b * 256 + i];
    sh_l[i] = shift[(size_t)b * 256 + i];
  }
  __syncthreads();
  for (int u = tid; u < 64 * 36; u += TPB) {
    int px = u / 36, ch = u - px * 36;
    int p = (pb << 6) + px;
    s8v v;
    if (ch < 32) {
      s8v raw = *(const s8v*)(x2raw + ((size_t)((b << 10) + p)) * 256 + ch * 8);
#pragma unroll
      for (int j = 0; j < 8; ++j) {
        int c = ch * 8 + j;
        float f = fmaxf(b2f((ushort_t)raw[j]) * sc_l[c] + sh_l[c], 0.f);
        v[j] = (short)f2b(f);
      }
    } else {
#pragma unroll
      for (int j = 0; j < 8; ++j) {
        int cg = ch * 8 + j;
        float fv;
        if (cg == 256)      fv = -1.f + (2.f / 31.f) * (float)(p & 31);
        else if (cg == 257) fv = -1.f + (2.f / 31.f) * (float)(p >> 5);
        else                fv = 0.f;
        v[j] = (short)f2b(fv);
      }
    }
    *(s8v*)(dst + ((size_t)((b << 10) + p)) * 288 + ch * 8) = v;
  }
}

// ---------------- bf16 MFMA GEMM (separate dispatch per projection) ----------------
// grid: 1D 768 blocks, XCD-swizzled: all 24 tiles of a batch on one XCD.
template <int MODE>
__global__ __launch_bounds__(TPB) void k_gemm_mfma(const ushort_t* __restrict__ A,
                                                   const ushort_t* __restrict__ Bw,
                                                   void* __restrict__ Cout,
                                                   const float* __restrict__ bias,
                                                   const float* __restrict__ mod) {
  const int wg = blockIdx.x;            // 0..767
  const int xcd = wg & 7;
  const int s2 = wg >> 3;               // 0..95
  const int b = xcd * 4 + (s2 / 24);
  const int rem = s2 - (s2 / 24) * 24;  // 0..23
  const int n0 = (rem % 3) << 7;
  const int m0 = (rem / 3) << 7;
  const int tid = threadIdx.x;
  const int w = tid >> 6, lane = tid & 63;
  const int wr = w >> 1, wc = w & 1;
  const int lhi = lane >> 4, llo = lane & 15;

  __shared__ ushort_t A_l[128][40];
  __shared__ ushort_t B_l[128][40];

  f4v acc[4][4];
#pragma unroll
  for (int i = 0; i < 4; ++i)
#pragma unroll
    for (int j = 0; j < 4; ++j) acc[i][j] = (f4v){0.f, 0.f, 0.f, 0.f};

  const ushort_t* Ab = A + (((size_t)b << 10)) * 288;

  for (int k0 = 0; k0 < 288; k0 += 32) {
    for (int u = tid; u < 512; u += TPB) {
      int row = u >> 2, seg = u & 3;
      *(s8v*)&A_l[row][seg * 8] = *(const s8v*)(Ab + (size_t)(m0 + row) * 288 + k0 + seg * 8);
      *(s8v*)&B_l[row][seg * 8] = *(const s8v*)(Bw + (size_t)(n0 + row) * 288 + k0 + seg * 8);
    }
    __syncthreads();
    s8v am[4], bn[4];
#pragma unroll
    for (int i = 0; i < 4; ++i) am[i] = *(const s8v*)&A_l[wr * 64 + i * 16 + llo][lhi * 8];
#pragma unroll
    for (int j = 0; j < 4; ++j) bn[j] = *(const s8v*)&B_l[wc * 64 + j * 16 + llo][lhi * 8];
#pragma unroll
    for (int i = 0; i < 4; ++i)
#pragma unroll
      for (int j = 0; j < 4; ++j) {
        if (MODE >= 2) acc[i][j] = MFMA16(bn[j], am[i], acc[i][j]);
        else           acc[i][j] = MFMA16(am[i], bn[j], acc[i][j]);
      }
    __syncthreads();
  }

  if (MODE == 1) {
    ushort_t* Cb = (ushort_t*)Cout + (size_t)b * 1024 * 288;
#pragma unroll
    for (int j = 0; j < 4; ++j) {
      int n = n0 + wc * 64 + j * 16 + llo;
      if (n >= 288) continue;
      bool real = n < VF_;
      float bv = real ? bias[n] : 0.f;
      float sm = real ? mod[(size_t)b * VF_ + n] : 0.f;
#pragma unroll
      for (int i = 0; i < 4; ++i)
#pragma unroll
        for (int r = 0; r < 4; ++r) {
          int m = m0 + wr * 64 + i * 16 + lhi * 4 + r;
          Cb[(size_t)m * 288 + n] = f2b(real ? (acc[i][j][r] + bv) * sm : 0.f);
        }
    }
  } else if (MODE == 2) {
    ushort_t* Cb = (ushort_t*)Cout + (size_t)b * 32 * 272 * 32;
#pragma unroll
    for (int j = 0; j < 4; ++j)
#pragma unroll
      for (int r = 0; r < 4; ++r) {
        int n = n0 + wc * 64 + j * 16 + lhi * 4 + r;
        if (n >= 272) continue;
        bool real = n < VF_;
        float bv = real ? bias[n] : 0.f;
#pragma unroll
        for (int i = 0; i < 4; ++i) {
          int m = m0 + wr * 64 + i * 16 + llo;
          int mc = m >> 5, mlo = m & 31;
          Cb[(((size_t)mc * 272 + n) << 5) + mlo] = f2b(real ? acc[i][j][r] + bv : 0.f);
        }
      }
  } else {
    float* Cf = (float*)Cout + (size_t)b * 300 * 1024;
#pragma unroll
    for (int j = 0; j < 4; ++j)
#pragma unroll
      for (int r = 0; r < 4; ++r) {
        int n = n0 + wc * 64 + j * 16 + lhi * 4 + r;
        if (n >= 300) continue;
        float bv = bias[n];
#pragma unroll
        for (int i = 0; i < 4; ++i) {
          int m = m0 + wr * 64 + i * 16 + llo;
          Cf[((size_t)n << 10) + m] = acc[i][j][r] + bv;
        }
      }
  }
}

// ---------------- txt cross-attention (vsr transposed [b][300][1024]) ----------------
__global__ __launch_bounds__(TPB) void k_txtattn(const float* __restrict__ vsrT,
                                                 const float* __restrict__ txt,
                                                 float* __restrict__ out) {
  const int b = blockIdx.y;
  const int p = blockIdx.x * TPB + threadIdx.x;
  __shared__ float tl[DS_ * LL];
  for (int i = threadIdx.x; i < DS_ * LL; i += TPB) tl[i] = txt[(size_t)b * DS_ * LL + i];
  __syncthreads();
  const float* vr = vsrT + ((size_t)b * DS_ << 10) + p;
  float lg[LL];
#pragma unroll
  for (int l = 0; l < LL; ++l) lg[l] = 0.f;
  for (int d = 0; d < DS_; d += 4) {
    float v0 = vr[(size_t)(d + 0) << 10];
    float v1 = vr[(size_t)(d + 1) << 10];
    float v2 = vr[(size_t)(d + 2) << 10];
    float v3 = vr[(size_t)(d + 3) << 10];
    const float* tr = tl + d * LL;
#pragma unroll
    for (int l = 0; l < LL; ++l)
      lg[l] += v0 * tr[l] + v1 * tr[l + 20] + v2 * tr[l + 40] + v3 * tr[l + 60];
  }
  const float sc = 0.057735026919f;
  float mx = lg[0] * sc;
#pragma unroll
  for (int l = 1; l < LL; ++l) mx = fmaxf(mx, lg[l] * sc);
  float sum = 0.f;
#pragma unroll
  for (int l = 0; l < LL; ++l) {
    lg[l] = __expf(lg[l] * sc - mx);
    sum += lg[l];
  }
  float inv = 1.f / sum;
#pragma unroll
  for (int l = 0; l < LL; ++l) lg[l] *= inv;
  float* ob = out + (((size_t)b * 558 + VF_) << 10) + p;
  for (int d = 0; d < DS_; ++d) {
    const float* tr = tl + d * LL;
    float s = 0.f;
#pragma unroll
    for (int l = 0; l < LL; ++l) s += lg[l] * tr[l];
    ob[(size_t)d << 10] = s;
  }
}

// ---------------- video self-attention: bf16 MFMA flash v4 ----------------
// K,Q: bf16 [b][1024][288]. Vt_blk: bf16 [b][32][272][32].
// Q AND V staged in LDS as fragment-contiguous 1KB blocks (throughput-floor b128 reads).
__global__ __launch_bounds__(256, 2) void k_flash_mfma(const ushort_t* __restrict__ Kb,
                                                       const ushort_t* __restrict__ Qb,
                                                       const ushort_t* __restrict__ Vtb,
                                                       float* __restrict__ out) {
  const int wg = blockIdx.x;           // 0..511
  const int xcd = wg & 7, s = wg >> 3;
  const int b = xcd * 4 + (s >> 4);
  const int n0 = (s & 15) << 6;
  const int tid = threadIdx.x;
  const int w = tid >> 6, lane = tid & 63;
  const int lhi = lane >> 4;
  const int llo = lane & 15;

  __shared__ ushort_t q_l[9 * 1032];   // frag-blocked Q (q0/q1 pairs per ks)
  __shared__ ushort_t v_l[17 * 520];   // frag-blocked V (17 × 512 + 8 pad)

  s8v kf[9];
  {
    const ushort_t* kp = Kb + ((size_t)(b * 1024 + n0 + w * 16 + llo)) * 288 + lhi * 8;
#pragma unroll
    for (int ks = 0; ks < 9; ++ks) kf[ks] = *(const s8v*)(kp + ks * 32);
  }

  const ushort_t* Qbase = Qb + (((size_t)b << 10)) * 288;
  const ushort_t* Vbase = Vtb + (size_t)b * 32 * 272 * 32;

  s8v qs[5], vs[5];
  auto ISSUE = [&](int mc) {
#pragma unroll
    for (int i = 0; i < 5; ++i) {
      int u = tid + (i << 8);
      if (u < 1152) qs[i] = *(const s8v*)(Qbase + (size_t)((mc << 5) + u / 36) * 288 + (u % 36) * 8);
      if (u < 1088) vs[i] = *(const s8v*)(Vbase + (size_t)mc * 8704 + (u << 3));
    }
  };
  auto WRITE = [&]() {
#pragma unroll
    for (int i = 0; i < 5; ++i) {
      int u = tid + (i << 8);
      if (u < 1152) {
        int r = u / 36, cq = u - r * 36;
        *(s8v*)&q_l[(cq >> 2) * 1032 + (r << 5) + ((cq & 3) << 3)] = qs[i];
      }
      if (u < 1088) *(s8v*)&v_l[(u << 3) + ((u >> 6) << 3)] = vs[i];
    }
  };

  f4v oacc[17];
#pragma unroll
  for (int i = 0; i < 17; ++i) oacc[i] = (f4v){0.f, 0.f, 0.f, 0.f};
  float mreg = -1e30f, lreg = 0.f;  // per-lane column n = n0 + w*16 + llo

  const float sc = 0.0622572819f;  // 1/sqrt(258)
  const int srcA = llo + ((lhi & 1) << 5);
  const int srcB = srcA + 16;
  const bool hi2 = lhi >= 2;
  const int qoff = (llo << 5) + (lhi << 3);  // lane offset within a 1KB fragment block

  ISSUE(0);
  WRITE();
  __syncthreads();
  ISSUE(1);

  for (int mc = 0; mc < 32; ++mc) {
    // S^T[m][n] via swapped QK^T
    f4v sacc0 = {0.f, 0.f, 0.f, 0.f}, sacc1 = {0.f, 0.f, 0.f, 0.f};
    __builtin_amdgcn_s_setprio(1);
#pragma unroll
    for (int ks = 0; ks < 9; ++ks) {
      s8v q0 = *(const s8v*)&q_l[ks * 1032 + qoff];
      s8v q1 = *(const s8v*)&q_l[ks * 1032 + 512 + qoff];
      sacc0 = MFMA16(q0, kf[ks], sacc0);
      sacc1 = MFMA16(q1, kf[ks], sacc1);
    }
    __builtin_amdgcn_s_setprio(0);

    // lane-local online softmax
    float pmax = fmaxf(fmaxf(fmaxf(sacc0[0], sacc0[1]), fmaxf(sacc0[2], sacc0[3])),
                       fmaxf(fmaxf(sacc1[0], sacc1[1]), fmaxf(sacc1[2], sacc1[3])));
    pmax = fmaxf(pmax, __shfl_xor(pmax, 16));
    pmax = fmaxf(pmax, __shfl_xor(pmax, 32));
    float mn = fmaxf(mreg, pmax * sc);
    float alpha = __expf(mreg - mn);
    mreg = mn;

    float p0[4], p1[4];
    float rsum = 0.f;
#pragma unroll
    for (int r = 0; r < 4; ++r) {
      p0[r] = __expf(sacc0[r] * sc - mn);
      p1[r] = __expf(sacc1[r] * sc - mn);
      rsum += p0[r] + p1[r];
    }
    rsum += __shfl_xor(rsum, 16);
    rsum += __shfl_xor(rsum, 32);
    lreg = lreg * alpha + rsum;

    // pack P -> bf16 PV B-fragment
    unsigned u0, u1, u2, u3;
    asm("v_cvt_pk_bf16_f32 %0, %1, %2" : "=v"(u0) : "v"(p0[0]), "v"(p0[1]));
    asm("v_cvt_pk_bf16_f32 %0, %1, %2" : "=v"(u1) : "v"(p0[2]), "v"(p0[3]));
    asm("v_cvt_pk_bf16_f32 %0, %1, %2" : "=v"(u2) : "v"(p1[0]), "v"(p1[1]));
    asm("v_cvt_pk_bf16_f32 %0, %1, %2" : "=v"(u3) : "v"(p1[2]), "v"(p1[3]));
    unsigned s0a = __shfl(u0, srcA, 64), s2a = __shfl(u2, srcA, 64);
    unsigned s1a = __shfl(u1, srcA, 64), s3a = __shfl(u3, srcA, 64);
    unsigned s0b = __shfl(u0, srcB, 64), s2b = __shfl(u2, srcB, 64);
    unsigned s1b = __shfl(u1, srcB, 64), s3b = __shfl(u3, srcB, 64);
    u4v pu;
    pu[0] = hi2 ? s2a : s0a;
    pu[1] = hi2 ? s3a : s1a;
    pu[2] = hi2 ? s2b : s0b;
    pu[3] = hi2 ? s3b : s1b;
    s8v pf = __builtin_bit_cast(s8v, pu);

    // PV: O^T[d][n] += V_frag * P  (V from LDS frag blocks)
    __builtin_amdgcn_s_setprio(1);
#pragma unroll
    for (int dt = 0; dt < 17; ++dt) {
      s8v vf = *(const s8v*)&v_l[dt * 520 + qoff];
      f4v o = oacc[dt];
      o[0] *= alpha; o[1] *= alpha; o[2] *= alpha; o[3] *= alpha;
      oacc[dt] = MFMA16(vf, pf, o);
    }
    __builtin_amdgcn_s_setprio(0);

    __syncthreads();  // all waves done reading chunk mc from LDS
    if (mc < 31) {
      WRITE();        // chunk mc+1 -> LDS
      __syncthreads();
      if (mc < 30) ISSUE(mc + 2);
    }
  }

  // epilogue
  float linv = 1.f / lreg;
  const int n = n0 + w * 16 + llo;
#pragma unroll
  for (int dt = 0; dt < 17; ++dt) {
#pragma unroll
    for (int r = 0; r < 4; ++r) {
      int d = dt * 16 + lhi * 4 + r;
      if (d < VF_) out[((size_t)(b * 558 + d) << 10) + n] = oacc[dt][r] * linv;
    }
  }
}

// ---------------- launcher ----------------
extern "C" void kernel_launch(void* const* d_in, const int* in_sizes, int n_in,
                              void* d_out, int out_size, void* d_ws, size_t ws_size,
                              hipStream_t stream) {
  const float* spatial = (const float*)d_in[0];
  const float* video   = (const float*)d_in[1];
  const float* txt     = (const float*)d_in[2];
  const float* c1w = (const float*)d_in[3];
  const float* c1b = (const float*)d_in[4];
  const float* g1g = (const float*)d_in[5];
  const float* g1b = (const float*)d_in[6];
  const float* c2w = (const float*)d_in[7];
  const float* c2b = (const float*)d_in[8];
  const float* g2g = (const float*)d_in[9];
  const float* g2b = (const float*)d_in[10];
  const float* rw  = (const float*)d_in[11];
  const float* rb  = (const float*)d_in[12];
  const float* kw  = (const float*)d_in[13];
  const float* kb  = (const float*)d_in[14];
  const float* qw  = (const float*)d_in[15];
  const float* qb  = (const float*)d_in[16];
  const float* vw  = (const float*)d_in[17];
  const float* vb  = (const float*)d_in[18];
  const float* iw  = (const float*)d_in[19];
  const float* ib  = (const float*)d_in[20];
  float* out = (float*)d_out;
  float* ws = (float*)d_ws;

  // ws layout (float offsets), lifetime-aliased
  ushort_t* x0h    = (ushort_t*)(ws + 0);          // [0, 4.72M) -> conv1
  float*    vsr    = ws + 0;                       // [0, 9.83M)  (transposed [300][1024]) after x1h dead
  float*    y1     = ws + 5000000;                 // [5.0M, 9.2M)
  ushort_t* x1h    = (ushort_t*)(ws + 9300000);    // [9.3M, 11.4M)
  ushort_t* kb16   = (ushort_t*)(ws + 10000000);   // [10.0M, 14.72M)  after x1h dead
  ushort_t* x2raw  = (ushort_t*)(ws + 11500000);   // [11.5M, 15.7M)
  ushort_t* qb16   = (ushort_t*)(ws + 15800000);   // [15.8M, 20.52M)  after x2raw dead? no—x2raw dies after vsoh
  ushort_t* vsoh   = (ushort_t*)(ws + 20600000);   // [20.6M, 25.32M)
  ushort_t* vtb16  = (ushort_t*)(ws + 25400000);   // [25.4M, 29.86M)
  ushort_t* wcat   = (ushort_t*)(ws + 29900000);   // 4*110592 us
  ushort_t* w1r    = (ushort_t*)(ws + 30140000);
  ushort_t* w2r    = (ushort_t*)(ws + 30310000);
  float*    mod    = ws + 30460000;                // 8,256
  float*    stats1 = ws + 30500000;                // 131,072
  float*    stats2 = ws + 30700000;                // 262,144
  float*    scale1 = ws + 31000000;                // 4,096
  float*    shift1 = ws + 31010000;                // 4,096
  float*    scale2 = ws + 31020000;                // 8,192
  float*    shift2 = ws + 31030000;                // 8,192

  // all prep (weights, mod, concat) in one dispatch
  k_prep<<<dim3(4720), TPB, 0, stream>>>(c1w, c2w, rw, kw, qw, vw, txt, iw, ib,
                                         video, spatial,
                                         w1r, w2r, wcat, mod, x0h);

  // conv1 (MFMA + GN stats, fp32 c-major); finalize; transpose+GN+relu -> x1h
  k_conv_mfma<36, 0><<<dim3(16, 1, NB), TPB, 0, stream>>>(x0h, w1r, c1b, (void*)y1, stats1, C1);
  k_gnfin<<<dim3(32, NB), 64, 0, stream>>>(stats1, g1g, g1b, scale1, shift1, C1, 4);
  k_to_nhwc128<<<dim3(16, NB), TPB, 0, stream>>>(y1, scale1, shift1, x1h);

  // conv2 (MFMA + GN stats, raw bf16 NHWC out); finalize; vsoh (GN+relu+coords, streaming)
  k_conv_mfma<16, 1><<<dim3(16, 2, NB), TPB, 0, stream>>>(x1h, w2r, c2b, (void*)x2raw, stats2, C2);
  k_gnfin<<<dim3(32, NB), 64, 0, stream>>>(stats2, g2g, g2b, scale2, shift2, C2, 8);
  k_build_vsoh<<<dim3(16, NB), TPB, 0, stream>>>(x2raw, scale2, shift2, vsoh);

  // 4 projections, separate template dispatches, XCD-swizzled 1D grid
  k_gemm_mfma<3><<<dim3(768), TPB, 0, stream>>>(vsoh, wcat + 0 * 110592, (void*)vsr, rb, nullptr);
  k_gemm_mfma<1><<<dim3(768), TPB, 0, stream>>>(vsoh, wcat + 1 * 110592, (void*)kb16, kb, mod);
  k_gemm_mfma<1><<<dim3(768), TPB, 0, stream>>>(vsoh, wcat + 2 * 110592, (void*)qb16, qb, mod);
  k_gemm_mfma<2><<<dim3(768), TPB, 0, stream>>>(vsoh, wcat + 3 * 110592, (void*)vtb16, vb, nullptr);

  // txt attention -> out channels [258, 558)
  k_txtattn<<<dim3(4, NB), TPB, 0, stream>>>(vsr, txt, out);

  // video self-attention (bf16 MFMA flash) -> out channels [0, 258)
  k_flash_mfma<<<dim3(512), 256, 0, stream>>>(kb16, qb16, vtb16, out);
}